// Round 20
// baseline (5649.188 us; speedup 1.0000x reference)
//
#include <hip/hip_runtime.h>

#define T_LEN 16384
#define BATCH 32
#define HID 32
#define L2E 1.44269504088896340736f
#define SCLG (-2.0f * 1.44269504088896340736f)   // -2*log2e

typedef float f2 __attribute__((ext_vector_type(2)));
typedef unsigned u2_t __attribute__((ext_vector_type(2)));

#if __has_builtin(__builtin_amdgcn_exp2f)
#define EXP2F(x) __builtin_amdgcn_exp2f(x)
#else
#define EXP2F(x) __exp2f(x)
#endif
#if __has_builtin(__builtin_amdgcn_rcpf)
#define RCPF(x) __builtin_amdgcn_rcpf(x)
#else
#define RCPF(x) (1.0f / (x))
#endif

#if __has_builtin(__builtin_amdgcn_sched_barrier)
#define SCHED_FENCE() __builtin_amdgcn_sched_barrier(0)
#else
#define SCHED_FENCE()
#endif

__device__ __forceinline__ float rlane(float v, int lane) {
    return __int_as_float(__builtin_amdgcn_readlane(__float_as_int(v), lane));
}

// Cross-half exchange (lower->upper), VALU pipe. Convention verified r4/r5.
__device__ __forceinline__ float xhalf_lo_to_hi(float v) {
#if __has_builtin(__builtin_amdgcn_permlane32_swap)
    u2_t r = __builtin_amdgcn_permlane32_swap(__float_as_uint(v), __float_as_uint(v),
                                              false, false);
    return __uint_as_float(r.x);
#else
    return __shfl_xor(v, 32, 64);
#endif
}

// r20 = r19 woven dual-sequence + sched_barrier(0) FENCES.
// r18/r19 lesson: the machine scheduler re-serializes the weave (sinks B's
// reads to their uses to cut live ranges — VGPR stayed 132 both times,
// wall = 2x403 serial). In-order wave issue makes static order everything;
// sched_barrier(0) pins it. Three fences per step:
//   [x-contrib + ALL 32 reads] || [64 interleaved pk dots] ||
//   [interleaved activation tails] || publishes
// B's reads can no longer sink below A's dots; one shared DS drain, dots
// issue-bound, tails latency-interleaved. Expect ~380-430 cyc per TWO steps.
// Tell for success: VGPR ~190-240 (both batches' h-regs live).
__global__ __launch_bounds__(64) __attribute__((amdgpu_waves_per_eu(1, 1)))
void lstm_seq_kernel(const float* __restrict__ x,
                     const float* __restrict__ W_ih,
                     const float* __restrict__ W_hh,
                     const float* __restrict__ b_ih,
                     const float* __restrict__ b_hh,
                     const float* __restrict__ W_out,
                     const float* __restrict__ b_out,
                     float* __restrict__ out)
{
    const int blk  = blockIdx.x;          // 16 blocks, 2 batches each
    const int lane = threadIdx.x;
    const int j    = lane & 31;
    const bool upper = (lane >= 32);

    // torch gate order: [0,32)=i [32,64)=f [64,96)=g [96,128)=o
    const int rowA = upper ? (32 + j) : j;        // f : i   (both sigmoid)
    const int rowB = upper ? (96 + j) : (64 + j); // o : g   (sigmoid : tanh)

    const float sclA = -L2E;
    const float sclB = upper ? -L2E : SCLG;

    // W rows as float2 pairs (pre-scaled), pinned resident — shared by both
    // batches.
    f2 Wa2[16], Wb2[16];
    const f2* ra2 = reinterpret_cast<const f2*>(W_hh + (size_t)rowA * HID);
    const f2* rb2 = reinterpret_cast<const f2*>(W_hh + (size_t)rowB * HID);
    #pragma unroll
    for (int q = 0; q < 16; ++q) { Wa2[q] = ra2[q] * sclA; Wb2[q] = rb2[q] * sclB; }
    #pragma unroll
    for (int q = 0; q < 16; ++q) { asm("" : "+v"(Wa2[q]), "+v"(Wb2[q])); }

    const float wihA = sclA * W_ih[rowA];
    const float wihB = sclB * W_ih[rowB];
    const float bA = sclA * (b_ih[rowA] + b_hh[rowA]);
    const float bB = sclB * (b_ih[rowB] + b_hh[rowB]);

    const float wout = W_out[j];
    const float bout = b_out[0];

    __shared__ float phistA[64 * 65];
    __shared__ float phistB[64 * 65];
    __shared__ float hbufA[64];   // fixed-address, single writer (r15 lesson)
    __shared__ float hbufB[64];

    float cSA = 0.0f, cSB = 0.0f;   // scaled cell state, upper lanes
    hbufA[lane] = 0.0f;
    hbufB[lane] = 0.0f;
    __syncthreads();

    const float* xA = x + (size_t)(2 * blk) * T_LEN;
    const float* xB = x + (size_t)(2 * blk + 1) * T_LEN;
    float*       yA = out + (size_t)(2 * blk) * T_LEN;
    float*       yB = out + (size_t)(2 * blk + 1) * T_LEN;

    const f2* hb2A = reinterpret_cast<const f2*>(&hbufA[32]);
    const f2* hb2B = reinterpret_cast<const f2*>(&hbufB[32]);

    float xvA = xA[lane];
    float xvB = xB[lane];

    for (int t0 = 0; t0 < T_LEN; t0 += 64) {
        float xvA_n = (t0 + 64 < T_LEN) ? xA[t0 + 64 + lane] : 0.0f;
        float xvB_n = (t0 + 64 < T_LEN) ? xB[t0 + 64 + lane] : 0.0f;

        #pragma unroll 2
        for (int s = 0; s < 64; ++s) {
            // ==== SECTION 1: x contributions + ALL 32 broadcast reads ====
            const float xsA = rlane(xvA, s);
            const float xsB = rlane(xvB, s);
            const float xpAA = fmaf(xsA, wihA, bA);
            const float xpBA = fmaf(xsA, wihB, bB);
            const float xpAB = fmaf(xsB, wihA, bA);
            const float xpBB = fmaf(xsB, wihB, bB);

            f2 hvA[16], hvB[16];
            #pragma unroll
            for (int p = 0; p < 16; ++p) hvA[p] = hb2A[p];
            #pragma unroll
            for (int p = 0; p < 16; ++p) hvB[p] = hb2B[p];

            SCHED_FENCE();   // B's reads may NOT sink below A's dots

            // ==== SECTION 2: 64 interleaved pk dots ====
            f2 zAA[4], zBA[4], zAB[4], zBB[4];
            zAA[0].x = xpAA; zAA[0].y = 0.0f;
            zBA[0].x = xpBA; zBA[0].y = 0.0f;
            zAB[0].x = xpAB; zAB[0].y = 0.0f;
            zBB[0].x = xpBB; zBB[0].y = 0.0f;
            #pragma unroll
            for (int p = 0; p < 16; ++p) {
                if (p == 0) {
                    asm("v_pk_fma_f32 %0, %1, %2, %0"
                        : "+v"(zAA[0]) : "v"(hvA[0]), "v"(Wa2[0]));
                    asm("v_pk_fma_f32 %0, %1, %2, %0"
                        : "+v"(zAB[0]) : "v"(hvB[0]), "v"(Wa2[0]));
                    asm("v_pk_fma_f32 %0, %1, %2, %0"
                        : "+v"(zBA[0]) : "v"(hvA[0]), "v"(Wb2[0]));
                    asm("v_pk_fma_f32 %0, %1, %2, %0"
                        : "+v"(zBB[0]) : "v"(hvB[0]), "v"(Wb2[0]));
                } else if (p < 4) {
                    asm("v_pk_mul_f32 %0, %1, %2"
                        : "=v"(zAA[p]) : "v"(hvA[p]), "v"(Wa2[p]));
                    asm("v_pk_mul_f32 %0, %1, %2"
                        : "=v"(zAB[p]) : "v"(hvB[p]), "v"(Wa2[p]));
                    asm("v_pk_mul_f32 %0, %1, %2"
                        : "=v"(zBA[p]) : "v"(hvA[p]), "v"(Wb2[p]));
                    asm("v_pk_mul_f32 %0, %1, %2"
                        : "=v"(zBB[p]) : "v"(hvB[p]), "v"(Wb2[p]));
                } else {
                    asm("v_pk_fma_f32 %0, %1, %2, %0"
                        : "+v"(zAA[p & 3]) : "v"(hvA[p]), "v"(Wa2[p]));
                    asm("v_pk_fma_f32 %0, %1, %2, %0"
                        : "+v"(zAB[p & 3]) : "v"(hvB[p]), "v"(Wa2[p]));
                    asm("v_pk_fma_f32 %0, %1, %2, %0"
                        : "+v"(zBA[p & 3]) : "v"(hvA[p]), "v"(Wb2[p]));
                    asm("v_pk_fma_f32 %0, %1, %2, %0"
                        : "+v"(zBB[p & 3]) : "v"(hvB[p]), "v"(Wb2[p]));
                }
            }
            const f2 rAA = (zAA[0] + zAA[1]) + (zAA[2] + zAA[3]);
            const f2 rBA = (zBA[0] + zBA[1]) + (zBA[2] + zBA[3]);
            const f2 rAB = (zAB[0] + zAB[1]) + (zAB[2] + zAB[3]);
            const f2 rBB = (zBB[0] + zBB[1]) + (zBB[2] + zBB[3]);
            const float zaA = rAA.x + rAA.y;
            const float zbA = rBA.x + rBA.y;
            const float zaB = rAB.x + rAB.y;
            const float zbB = rBB.x + rBB.y;

            SCHED_FENCE();   // keep both dot sets ahead of the tails

            // ==== SECTION 3: interleaved activation tails ====
            const float AA = RCPF(1.0f + EXP2F(zaA));
            const float AB = RCPF(1.0f + EXP2F(zaB));
            const float rA = RCPF(1.0f + EXP2F(zbA));
            const float rB = RCPF(1.0f + EXP2F(zbB));
            const float tgSA = fmaf(rA, 2.0f * SCLG, -SCLG);
            const float tgSB = fmaf(rB, 2.0f * SCLG, -SCLG);
            const float so2A = rA + rA;
            const float so2B = rB + rB;

            const float upA = AA * tgSA;
            const float upB = AB * tgSB;
            const float tuA = xhalf_lo_to_hi(upA);
            const float tuB = xhalf_lo_to_hi(upB);

            cSA = fmaf(AA, cSA, tuA);
            cSB = fmaf(AB, cSB, tuB);
            const float r2A = RCPF(1.0f + EXP2F(cSA));
            const float r2B = RCPF(1.0f + EXP2F(cSB));
            const float hA  = fmaf(so2A, r2A, -rA);
            const float hB  = fmaf(so2B, r2B, -rB);

            SCHED_FENCE();   // publishes stay last

            // ==== SECTION 4: publishes ====
            hbufA[lane] = hA;
            hbufB[lane] = hB;
            phistA[s * 65 + lane] = hA * wout;
            phistB[s * 65 + lane] = hB * wout;
        }

        __syncthreads();  // single wave: cheap; publish both phists
        {
            float accA = bout, accB = bout;
            #pragma unroll
            for (int k = 0; k < HID; ++k) {
                accA += phistA[lane * 65 + 32 + k];
                accB += phistB[lane * 65 + 32 + k];
            }
            yA[t0 + lane] = accA;
            yB[t0 + lane] = accB;
        }
        __syncthreads();  // protect phists before next chunk rewrites them

        xvA = xvA_n;
        xvB = xvB_n;
    }
}

extern "C" void kernel_launch(void* const* d_in, const int* in_sizes, int n_in,
                              void* d_out, int out_size, void* d_ws, size_t ws_size,
                              hipStream_t stream) {
    const float* x     = (const float*)d_in[0];
    const float* W_ih  = (const float*)d_in[1];
    const float* W_hh  = (const float*)d_in[2];
    const float* b_ih  = (const float*)d_in[3];
    const float* b_hh  = (const float*)d_in[4];
    const float* W_out = (const float*)d_in[5];
    const float* b_out = (const float*)d_in[6];
    float* out = (float*)d_out;

    lstm_seq_kernel<<<BATCH / 2, 64, 0, stream>>>(x, W_ih, W_hh, b_ih, b_hh,
                                                  W_out, b_out, out);
}

// Round 21
// 3081.527 us; speedup vs baseline: 1.8332x; 1.8332x over previous
//
#include <hip/hip_runtime.h>

#define T_LEN 16384
#define BATCH 32
#define HID 32
#define L2E 1.44269504088896340736f
#define SCLG (-2.0f * 1.44269504088896340736f)   // -2*log2e

typedef float f2 __attribute__((ext_vector_type(2)));
typedef unsigned u2_t __attribute__((ext_vector_type(2)));

#if __has_builtin(__builtin_amdgcn_exp2f)
#define EXP2F(x) __builtin_amdgcn_exp2f(x)
#else
#define EXP2F(x) __exp2f(x)
#endif
#if __has_builtin(__builtin_amdgcn_rcpf)
#define RCPF(x) __builtin_amdgcn_rcpf(x)
#else
#define RCPF(x) (1.0f / (x))
#endif

__device__ __forceinline__ float rlane(float v, int lane) {
    return __int_as_float(__builtin_amdgcn_readlane(__float_as_int(v), lane));
}

// Cross-half exchange (lower->upper), VALU pipe. Convention verified r4/r5:
// builtin returns {vdst_new, vsrc_new}; r.x has lanes 32-63 = old lanes 0-31.
__device__ __forceinline__ float xhalf_lo_to_hi(float v) {
#if __has_builtin(__builtin_amdgcn_permlane32_swap)
    u2_t r = __builtin_amdgcn_permlane32_swap(__float_as_uint(v), __float_as_uint(v),
                                              false, false);
    return __uint_as_float(r.x);
#else
    return __shfl_xor(v, 32, 64);
#endif
}

// FINAL (r21 = r16 verbatim, best measured: 3063us, 449 cyc/step).
// Session ledger (what's IN and why):
//  - one wave per batch; lane j<32: gates (i,g); lane 32+j: (f,o)+state
//  - h broadcast: ds_write to FIXED-address hbuf + 16 wave-uniform f2
//    broadcast reads (r11: -14% vs 32x readlane->SGPR hazard chain;
//    r15: merging into row-varying phist kills alias analysis — keep split)
//  - dots: 32 v_pk_fma_f32 via asm, 4-way split accumulators (r7: -12%)
//  - weights pre-scaled by -log2e/-2log2e; scaled cell cS; h via single fma
//    (r14/r16 tail algebra: -20 cyc/step)
//  - weights pinned resident w/ waves_per_eu(1,1) (r9: small win)
// Refuted/regressed (do NOT retry): forced residency w/o clamp (r6 scratch),
// hw-exp asm (r10 null), f2-feed movs (r12 null), K-split (r13 +80cyc),
// read/consume fusion (r17 +44cyc), dual-recurrence per wave in any form
// (r18/r19/r20: scheduler re-serializes; VGPR stays 132, wall = 2x serial).
// Structural floor: ~290 cyc serial chain (DS round-trip + 2 dependent
// transcendental segments) + ~160 cyc non-overlapped issue, one wave/CU.
__global__ __launch_bounds__(64) __attribute__((amdgpu_waves_per_eu(1, 1)))
void lstm_seq_kernel(const float* __restrict__ x,
                     const float* __restrict__ W_ih,
                     const float* __restrict__ W_hh,
                     const float* __restrict__ b_ih,
                     const float* __restrict__ b_hh,
                     const float* __restrict__ W_out,
                     const float* __restrict__ b_out,
                     float* __restrict__ out)
{
    const int b    = blockIdx.x;
    const int lane = threadIdx.x;
    const int j    = lane & 31;
    const bool upper = (lane >= 32);

    // torch gate order in W_ih/W_hh rows: [0,32)=i [32,64)=f [64,96)=g [96,128)=o
    const int rowA = upper ? (32 + j) : j;        // f : i   (both sigmoid)
    const int rowB = upper ? (96 + j) : (64 + j); // o : g   (sigmoid : tanh)

    // Pre-scale: sigmoid rows by -L2E; tanh row (g, lower B) by -2*L2E.
    const float sclA = -L2E;
    const float sclB = upper ? -L2E : SCLG;

    // W rows as float2 pairs (pre-scaled), pinned resident
    f2 Wa2[16], Wb2[16];
    const f2* ra2 = reinterpret_cast<const f2*>(W_hh + (size_t)rowA * HID);
    const f2* rb2 = reinterpret_cast<const f2*>(W_hh + (size_t)rowB * HID);
    #pragma unroll
    for (int q = 0; q < 16; ++q) { Wa2[q] = ra2[q] * sclA; Wb2[q] = rb2[q] * sclB; }
    #pragma unroll
    for (int q = 0; q < 16; ++q) { asm("" : "+v"(Wa2[q]), "+v"(Wb2[q])); }

    const float wihA = sclA * W_ih[rowA];
    const float wihB = sclB * W_ih[rowB];
    const float bA = sclA * (b_ih[rowA] + b_hh[rowA]);
    const float bB = sclB * (b_ih[rowB] + b_hh[rowB]);

    const float wout = W_out[j];
    const float bout = b_out[0];

    // phist[s][lane], stride 65: store banks (s+l)%32 conflict-free;
    // flush read phist[l*65+32+k] banks (l+k)%32 conflict-free.
    __shared__ float phist[64 * 65];
    // h-broadcast buffer: FIXED address, single writer per slot.
    __shared__ float hbuf[64];

    float cS = 0.0f;             // cS = -2log2e * c, state in upper lanes
    hbuf[lane] = 0.0f;           // seed h_0 = 0
    __syncthreads();

    const float* xb = x + (size_t)b * T_LEN;
    float*       yb = out + (size_t)b * T_LEN;
    // wave-uniform broadcast-read base (h values live at hbuf[32..63]),
    // read as f2 pairs -> register pairs that ARE the pk_fma operands.
    const f2* hb2 = reinterpret_cast<const f2*>(&hbuf[32]);

    float xv = xb[lane];  // 64 timesteps of x per lane-chunk

    for (int t0 = 0; t0 < T_LEN; t0 += 64) {
        float xv_next = (t0 + 64 < T_LEN) ? xb[t0 + 64 + lane] : 0.0f;

        #pragma unroll 4
        for (int s = 0; s < 64; ++s) {
            // x contribution: independent of h, schedules off-chain
            const float xs  = rlane(xv, s);
            const float xpA = fmaf(xs, wihA, bA);
            const float xpB = fmaf(xs, wihB, bB);

            // broadcast read: 16 f2 loads, wave-uniform, conflict-free,
            // pipelined; each lands as an even-aligned VGPR pair.
            f2 hv2[16];
            #pragma unroll
            for (int p = 0; p < 16; ++p) hv2[p] = hb2[p];

            // dots: 32 pure-VGPR v_pk_fma_f32, 4-way split accumulators;
            // accumulator 0 starts at {xp, 0} (x/bias folded in).
            f2 zA[4], zB[4];
            zA[0].x = xpA; zA[0].y = 0.0f;
            zB[0].x = xpB; zB[0].y = 0.0f;
            #pragma unroll
            for (int p = 0; p < 16; ++p) {
                if (p == 0) {
                    asm("v_pk_fma_f32 %0, %1, %2, %0"
                        : "+v"(zA[0]) : "v"(hv2[0]), "v"(Wa2[0]));
                    asm("v_pk_fma_f32 %0, %1, %2, %0"
                        : "+v"(zB[0]) : "v"(hv2[0]), "v"(Wb2[0]));
                } else if (p < 4) {
                    asm("v_pk_mul_f32 %0, %1, %2"
                        : "=v"(zA[p]) : "v"(hv2[p]), "v"(Wa2[p]));
                    asm("v_pk_mul_f32 %0, %1, %2"
                        : "=v"(zB[p]) : "v"(hv2[p]), "v"(Wb2[p]));
                } else {
                    asm("v_pk_fma_f32 %0, %1, %2, %0"
                        : "+v"(zA[p & 3]) : "v"(hv2[p]), "v"(Wa2[p]));
                    asm("v_pk_fma_f32 %0, %1, %2, %0"
                        : "+v"(zB[p & 3]) : "v"(hv2[p]), "v"(Wb2[p]));
                }
            }
            const f2 rA = (zA[0] + zA[1]) + (zA[2] + zA[3]);
            const f2 rB = (zB[0] + zB[1]) + (zB[2] + zB[3]);
            const float za = rA.x + rA.y;   // pre-scaled gate input
            const float zb = rB.x + rB.y;

            // A = sigmoid (i lower / f upper): rcp(1+exp2(za))
            const float A = RCPF(1.0f + EXP2F(za));
            const float r = RCPF(1.0f + EXP2F(zb));
            // lower: tgS = -2log2e*tanh(g) = fma(r, 2SCLG, -SCLG)
            const float tgS = fmaf(r, 2.0f * SCLG, -SCLG);
            const float so2 = r + r;               // 2*so (upper), off-chain

            // lower: u' = A*tgS = -2log2e*(si*tg); ship to upper (VALU swap)
            const float up = A * tgS;
            const float tu = xhalf_lo_to_hi(up);

            // upper: cS = sf*cS + u'; tanh(c) via exp2(cS) direct
            cS = fmaf(A, cS, tu);
            const float r2 = RCPF(1.0f + EXP2F(cS));
            const float h  = fmaf(so2, r2, -r);    // so*tanh(c)

            hbuf[lane] = h;                    // publish FIRST (gates next step)
            phist[s * 65 + lane] = h * wout;   // deferred output (off-chain)
        }

        __syncthreads();  // single wave: cheap; publish phist
        float acc = bout;
        #pragma unroll
        for (int k = 0; k < HID; ++k) acc += phist[lane * 65 + 32 + k];
        yb[t0 + lane] = acc;
        __syncthreads();  // protect phist before next chunk rewrites it

        xv = xv_next;
    }
}

extern "C" void kernel_launch(void* const* d_in, const int* in_sizes, int n_in,
                              void* d_out, int out_size, void* d_ws, size_t ws_size,
                              hipStream_t stream) {
    const float* x     = (const float*)d_in[0];
    const float* W_ih  = (const float*)d_in[1];
    const float* W_hh  = (const float*)d_in[2];
    const float* b_ih  = (const float*)d_in[3];
    const float* b_hh  = (const float*)d_in[4];
    const float* W_out = (const float*)d_in[5];
    const float* b_out = (const float*)d_in[6];
    float* out = (float*)d_out;

    lstm_seq_kernel<<<BATCH, 64, 0, stream>>>(x, W_ih, W_hh, b_ih, b_hh,
                                              W_out, b_out, out);
}